// Round 8
// baseline (832.323 us; speedup 1.0000x reference)
//
#include <hip/hip_runtime.h>
#include <stdint.h>

typedef short v8s __attribute__((ext_vector_type(8)));
typedef float v4f __attribute__((ext_vector_type(4)));

__device__ __forceinline__ float bf2f(short s) {
    unsigned int u = ((unsigned int)(unsigned short)s) << 16;
    float f; __builtin_memcpy(&f, &u, 4); return f;
}
__device__ __forceinline__ unsigned short f2bf_rne(float f) {
    unsigned int u; __builtin_memcpy(&u, &f, 4);
    return (unsigned short)((u + 0x7FFFu + ((u >> 16) & 1u)) >> 16);
}
__device__ __forceinline__ unsigned short f2bf_rhu(float f) {  // round-half-up (2 ops)
    unsigned int u; __builtin_memcpy(&u, &f, 4);
    return (unsigned short)((u + 0x8000u) >> 16);
}
__device__ __forceinline__ unsigned short f2bf_trunc(float f) {  // 1 op
    unsigned int u; __builtin_memcpy(&u, &f, 4);
    return (unsigned short)(u >> 16);
}
__device__ __forceinline__ float tanh_fast(float z) {
    float e = __expf(2.0f * z);
    float r = __builtin_amdgcn_rcpf(e + 1.0f);
    return __builtin_fmaf(-2.0f, r, 1.0f);
}

// ---------------------------------------------------------------------------
// Phase A: ux[t][b][i] = sum_e x[b][t][e]*Uw[i][e] + Ub[i] + Wb[i]   (f32)
// Block 0 additionally zeroes the sync area (ticket + per-tile flags).
// ---------------------------------------------------------------------------
__global__ __launch_bounds__(256) void ux_kernel(
    const float* __restrict__ x, const float* __restrict__ Uw,
    const float* __restrict__ Ub, const float* __restrict__ Wb,
    float* __restrict__ ux, unsigned* __restrict__ sync) {
    if (blockIdx.x == 0) {
        for (int i = threadIdx.x; i < 864; i += 256) sync[i] = 0;
    }
    int row = blockIdx.x * 2 + (threadIdx.x >> 7);  // row = t*32 + b
    int i = threadIdx.x & 127;
    int b = row & 31, t = row >> 5;
    const float* xr = x + (b * 200 + t) * 32;
    const float* ur = Uw + i * 32;
    float acc = 0.f;
#pragma unroll
    for (int e4 = 0; e4 < 8; ++e4) {
        v4f xv = *(const v4f*)(xr + e4 * 4);
        v4f uv = *(const v4f*)(ur + e4 * 4);
#pragma unroll
        for (int j = 0; j < 4; ++j) acc = __builtin_fmaf(xv[j], uv[j], acc);
    }
    ux[row * 128 + i] = acc + Ub[i] + Wb[i];
}

// ---------------------------------------------------------------------------
// Fused kernel, grid = 129 x 1024 threads, 80 KiB dynamic LDS -> exactly one
// block per CU (R6 precedent: dynamic-LDS cap is honored). 129 blocks < 256
// CUs, so producers own their CUs AND consumers get 16 waves/CU (2x the
// failed R6 level; total consumer waves = 127x16 = 2032 = same as R7).
//
// ROUND-8 CHANGE — wave-role split in the producer block. Across R1-R7 the
// invariant cost was hs-store drains + flag release ON the compute waves
// (every 4th barrier = vmcnt(0) of LLC-bound stores + tid0 flag serialization
// + barrier jitter). Now:
//   waves 0-7 : the R5 recurrence verbatim, MINUS every global store and
//               MINUS every vmcnt — pure LDS/MFMA/VALU + 2-deep ux prefetch,
//               raw lgkmcnt(0)+s_barrier each step, nothing else.
//   wave 8    : storer. Each step s>=1 reads the h written at step s-1 (the
//               hi plane) from LDS and issues 8x8B agent(sc1) stores to hs;
//               it ALONE runs s_waitcnt vmcnt(0) + the RELAXED flag add,
//               one tile behind, so drains never touch compute waves.
//   waves 9-15: barrier-matched idle (200 RAWBARs).
// Coherence protocol otherwise unchanged from R4-R7 (proven): sc1 stores ->
// LLC; vmcnt(0) before relaxed agent flag add; consumers relaxed-spin then
// ordinary loads (hs lines never cached locally).
//
// Consumers: R7 math, restructured as TWO independent halves per block
// (waves 0-7 / 8-15). Half h = logical consumer hcid = (ticket-2)*2 + h:
// v_tile = hcid&31 fixed (Vw frags hoisted), g = hcid>>5; halves of a block
// always share g (2c and 2c+1 never straddle a multiple of 32), so both
// halves walk the same tb chain in lockstep through block-wide barriers.
// Each half has its own LDS staging region (16640 B).
// ---------------------------------------------------------------------------
#define RAWBAR asm volatile("s_waitcnt lgkmcnt(0)\n\ts_barrier" ::: "memory")

__global__ __launch_bounds__(1024) void fused_kernel(
    const float* __restrict__ Ww, const float* __restrict__ ux,
    short* __restrict__ hs, float* __restrict__ hidden_out,
    const float* __restrict__ Vw, const float* __restrict__ Vb,
    float* __restrict__ out, unsigned* __restrict__ sync) {
    extern __shared__ char dls[];   // 81920 B requested at launch
    __shared__ unsigned s_ticket;
    const int tid = threadIdx.x;

    if (tid == 0)
        s_ticket = __hip_atomic_fetch_add(sync, 1u, __ATOMIC_RELAXED,
                                          __HIP_MEMORY_SCOPE_AGENT);
    __syncthreads();
    const unsigned ticket = s_ticket;

    const int w = tid >> 6, lane = tid & 63, q = lane >> 4, c = lane & 15;

    if (ticket < 2) {
        // ------------------------------ producer ------------------------------
        // LDS: [buf][hi/lo][row 16][col 136] shorts; buf 8704B, plane 4352B,
        // row 272B. Step t: t even writes buf1, t odd writes buf0.
        char* lds = dls;
        const int b0 = (int)ticket * 16;

        for (int i = tid; i < 1088; i += 1024)
            ((v8s*)lds)[i] = (v8s){0, 0, 0, 0, 0, 0, 0, 0};
        __syncthreads();

        if (w < 8) {
            // -------- compute waves: no global stores, no vmcnt, ever --------
            const int col = 16 * w + c;
            v8s w_hi[4], w_lo[4];
#pragma unroll
            for (int kb = 0; kb < 4; ++kb) {
                const float* p = Ww + col * 128 + 32 * kb + 8 * q;
#pragma unroll
                for (int j = 0; j < 8; ++j) {
                    float v = p[j];
                    unsigned short hi = f2bf_rne(v);
                    w_hi[kb][j] = (short)hi;
                    w_lo[kb][j] = (short)f2bf_rne(v - bf2f((short)hi));
                }
            }
            const int rd_base = c * 272 + 16 * q;    // A-frag: row c, k-off 8q
            const int wr_base = q * 1088 + col * 2;  // C rows 4q+r, col

            const float* uxp = ux + (b0 + 4 * q) * 128 + col;
            v4f uxA = {uxp[0], uxp[128], uxp[256], uxp[384]};
            v4f uxB = {uxp[4096], uxp[4224], uxp[4352], uxp[4480]};
            uxp += 8192;

#define RNN_STEP(RBUF, WBUF, UXS)                                                   \
    {                                                                               \
        v4f a0 = UXS;  /* consume loads issued 2 steps ago */                       \
        UXS[0] = uxp[0]; UXS[1] = uxp[128]; UXS[2] = uxp[256]; UXS[3] = uxp[384];   \
        v4f a1 = {0.f, 0.f, 0.f, 0.f}, a2 = a1;                                     \
        _Pragma("unroll") for (int kb = 0; kb < 4; ++kb) {                          \
            v8s ahi = *(const v8s*)(lds + (RBUF)*8704 + kb * 64 + rd_base);         \
            v8s alo = *(const v8s*)(lds + (RBUF)*8704 + 4352 + kb * 64 + rd_base);  \
            a0 = __builtin_amdgcn_mfma_f32_16x16x32_bf16(ahi, w_hi[kb], a0, 0, 0, 0); \
            a1 = __builtin_amdgcn_mfma_f32_16x16x32_bf16(ahi, w_lo[kb], a1, 0, 0, 0); \
            a2 = __builtin_amdgcn_mfma_f32_16x16x32_bf16(alo, w_hi[kb], a2, 0, 0, 0); \
        }                                                                           \
        _Pragma("unroll") for (int r = 0; r < 4; ++r) {                             \
            float z = (a0[r] + a1[r]) + a2[r];                                      \
            float h = tanh_fast(z);                                                 \
            unsigned short hh = f2bf_rhu(h);                                        \
            float rem = h - bf2f((short)hh);                                        \
            unsigned short hl = f2bf_trunc(rem);                                    \
            *(short*)(lds + (WBUF)*8704 + r * 272 + wr_base) = (short)hh;           \
            *(short*)(lds + (WBUF)*8704 + 4352 + r * 272 + wr_base) = (short)hl;    \
        }                                                                           \
        uxp += 4096;                                                                \
        RAWBAR;                                                                     \
    }

            for (int it = 0; it < 100; ++it) {
                RNN_STEP(0, 1, uxA)   // t even
                RNN_STEP(1, 0, uxB)   // t odd
                // prefetch reads up to 32KB past ux at the end (hs region of
                // d_ws): in-bounds of ws, values never used.
            }
#undef RNN_STEP

            // final h: t=199 wrote buf0; each lane reads its own writes
#pragma unroll
            for (int r = 0; r < 4; ++r) {
                short hh = *(short*)(lds + r * 272 + wr_base);
                short hl = *(short*)(lds + 4352 + r * 272 + wr_base);
                hidden_out[(b0 + 4 * q + r) * 128 + col] = bf2f(hh) + bf2f(hl);
            }
        } else if (w == 8) {
            // -------- storer wave: hs stores + drains + flags, one step behind
            for (int s = 0; s < 200; ++s) {
                if (s >= 5 && ((s - 5) & 3) == 0) {
                    // stores for tile (s-5)/4 (t = s-5 .. s-2) were all issued
                    // by iteration s-1 -> drain own vmcnt, publish.
                    asm volatile("s_waitcnt vmcnt(0)" ::: "memory");
                    if (lane == 0)
                        __hip_atomic_fetch_add(sync + 16 + ((s - 5) >> 2) * 16, 1u,
                                               __ATOMIC_RELAXED,
                                               __HIP_MEMORY_SCOPE_AGENT);
                }
                if (s >= 1) {
                    // h(t=s-1): t even -> buf1 <=> s odd
                    const char* src = lds + ((s & 1) ? 8704 : 0);
#pragma unroll
                    for (int jj = 0; jj < 4; ++jj) {
                        int row = 4 * jj + (lane >> 4);
                        const unsigned long long* p = (const unsigned long long*)
                            (src + row * 272 + (lane & 15) * 16);
                        unsigned long long v0 = p[0], v1 = p[1];
                        unsigned long long* d = (unsigned long long*)
                            (hs + (s - 1) * 4096 + (b0 + row) * 128 + (lane & 15) * 8);
                        __hip_atomic_store(d, v0, __ATOMIC_RELAXED,
                                           __HIP_MEMORY_SCOPE_AGENT);
                        __hip_atomic_store(d + 1, v1, __ATOMIC_RELAXED,
                                           __HIP_MEMORY_SCOPE_AGENT);
                    }
                }
                RAWBAR;
            }
            // t=199 (buf0), then final drain + last flags
            {
                const char* src = lds;   // t=199 odd -> buf0
#pragma unroll
                for (int jj = 0; jj < 4; ++jj) {
                    int row = 4 * jj + (lane >> 4);
                    const unsigned long long* p = (const unsigned long long*)
                        (src + row * 272 + (lane & 15) * 16);
                    unsigned long long v0 = p[0], v1 = p[1];
                    unsigned long long* d = (unsigned long long*)
                        (hs + 199 * 4096 + (b0 + row) * 128 + (lane & 15) * 8);
                    __hip_atomic_store(d, v0, __ATOMIC_RELAXED,
                                       __HIP_MEMORY_SCOPE_AGENT);
                    __hip_atomic_store(d + 1, v1, __ATOMIC_RELAXED,
                                       __HIP_MEMORY_SCOPE_AGENT);
                }
                asm volatile("s_waitcnt vmcnt(0)" ::: "memory");
                if (lane == 0) {
                    // tiles 48 (t=192..195, flagged at s=197? no: s=197 covers
                    // tile 48) — remaining tile 49 (t=196..199) publishes here.
                    __hip_atomic_fetch_add(sync + 16 + 49 * 16, 1u,
                                           __ATOMIC_RELAXED,
                                           __HIP_MEMORY_SCOPE_AGENT);
                }
            }
        } else {
            // -------- idle waves: barrier-matched (200 RAWBARs)
            for (int s = 0; s < 200; ++s) RAWBAR;
        }
        return;
    }

    // ------------------------------ consumer ------------------------------
    const int half = w >> 3;                      // 0 or 1
    const int wl = w & 7;                         // wave-in-half
    const int hcid = ((int)ticket - 2) * 2 + half;  // 0..253
    const int v_tile = hcid & 31;                 // FIXED per half
    const int g = hcid >> 5;                      // tb residue 0..7 (same for both halves)
    const int v_wave = v_tile * 256 + 32 * wl;
    float* ldsF = (float*)(dls + half * 16640);   // [16][260] f32 staging per half

    v8s afr[4][2];
#pragma unroll
    for (int kb = 0; kb < 4; ++kb)
#pragma unroll
        for (int vt = 0; vt < 2; ++vt) {
            int vr = v_wave + 16 * vt + c;
            vr = vr < 8000 ? vr : 7999;  // OOB rows: garbage acc, store-masked
            const float* ap = Vw + vr * 128 + 32 * kb + 8 * q;
            v4f p0 = *(const v4f*)ap;
            v4f p1 = *(const v4f*)(ap + 4);
#pragma unroll
            for (int j = 0; j < 4; ++j) {
                afr[kb][vt][j] = (short)f2bf_rne(p0[j]);
                afr[kb][vt][4 + j] = (short)f2bf_rne(p1[j]);
            }
        }
    v4f vbv[2];
#pragma unroll
    for (int vt = 0; vt < 2; ++vt) {
        int v4b = v_wave + 16 * vt + 4 * q;
        vbv[vt] = *(const v4f*)(Vb + (v4b < 8000 ? v4b : 0));
    }
    const int vcol = v_tile * 256 + 4 * lane;     // coalesced-store column
    const bool vok = vcol < 8000;

    auto do_tile = [&](int tb) {
        const int n0 = tb * 128;
        unsigned* flag = sync + 16 + tb * 16;
        if (tid == 0) {
            while (__hip_atomic_load(flag, __ATOMIC_RELAXED,
                                     __HIP_MEMORY_SCOPE_AGENT) < 2u)
                __builtin_amdgcn_s_sleep(32);
        }
        __syncthreads();

        v4f acc[2][8];
#pragma unroll
        for (int a = 0; a < 2; ++a)
#pragma unroll
            for (int b = 0; b < 8; ++b) acc[a][b] = (v4f){0.f, 0.f, 0.f, 0.f};

#pragma unroll
        for (int kb = 0; kb < 4; ++kb) {
#pragma unroll
            for (int nt = 0; nt < 8; ++nt) {
                v8s bfr = *(const v8s*)(hs + (n0 + 16 * nt + c) * 128 + 32 * kb + 8 * q);
                acc[0][nt] = __builtin_amdgcn_mfma_f32_16x16x32_bf16(afr[kb][0], bfr, acc[0][nt], 0, 0, 0);
                acc[1][nt] = __builtin_amdgcn_mfma_f32_16x16x32_bf16(afr[kb][1], bfr, acc[1][nt], 0, 0, 0);
            }
        }

        // Stage 16 rows in LDS, then 1KB-contiguous wave stores.
#pragma unroll
        for (int nt = 0; nt < 8; ++nt) {
#pragma unroll
            for (int vt = 0; vt < 2; ++vt) {
                v4f o;
#pragma unroll
                for (int r = 0; r < 4; ++r) o[r] = acc[vt][nt][r] + vbv[vt][r];
                *(v4f*)&ldsF[c * 260 + 32 * wl + 16 * vt + 4 * q] = o;
            }
            RAWBAR;  // LDS visible (lgkm only; global stores keep flying)
#pragma unroll
            for (int h2 = 0; h2 < 2; ++h2) {
                int row = wl + 8 * h2;          // wave-uniform row 0..15
                int n = n0 + 16 * nt + row;
                int t = n >> 5, b = n & 31;
                v4f o = *(const v4f*)&ldsF[row * 260 + 4 * lane];
                if (vok)
                    *(v4f*)(out + (size_t)(b * 200 + t) * 8000 + vcol) = o;
            }
            RAWBAR;  // reads done before next chunk overwrites
        }
    };

    for (int tb = g; tb < 50; tb += 8) do_tile(tb);
    // Patch: tiles (tb===7 mod 8, v in {30,31}) have no hcid=224+v owner.
    // hcid 30/31 are the two halves of block ticket==17 (cid 15) -> both run
    // the patch chain together, staying barrier-lockstep.
    if (hcid == 30 || hcid == 31)
        for (int tb = 7; tb < 50; tb += 8) do_tile(tb);
}

extern "C" void kernel_launch(void* const* d_in, const int* in_sizes, int n_in,
                              void* d_out, int out_size, void* d_ws, size_t ws_size,
                              hipStream_t stream) {
    const float* x  = (const float*)d_in[0];  // [32][200][32]
    const float* Ww = (const float*)d_in[1];  // [128][128]
    const float* Wb = (const float*)d_in[2];  // [128]
    const float* Uw = (const float*)d_in[3];  // [128][32]
    const float* Ub = (const float*)d_in[4];  // [128]
    const float* Vw = (const float*)d_in[5];  // [8000][128]
    const float* Vb = (const float*)d_in[6];  // [8000]
    float* out = (float*)d_out;               // [32][200][8000] ++ [32][128]

    float* ux = (float*)d_ws;                          // 819200 f32 = 3.277 MB
    short* hs = (short*)((char*)d_ws + 3276800);       // 819200 bf16 = 1.638 MB
    unsigned* sync = (unsigned*)((char*)d_ws + 4915200); // ticket + 50 flags

    ux_kernel<<<3200, 256, 0, stream>>>(x, Uw, Ub, Wb, ux, sync);
    // 80 KiB dynamic LDS -> one block per CU; 129 blocks -> private CUs.
    fused_kernel<<<129, 1024, 81920, stream>>>(Ww, ux, hs, out + 51200000,
                                               Vw, Vb, out, sync);
}